// Round 5
// baseline (331.124 us; speedup 1.0000x reference)
//
#include <hip/hip_runtime.h>
#include <hip/hip_bf16.h>
#include <stdint.h>
#include <math.h>

typedef __attribute__((ext_vector_type(4))) float f32x4;
typedef __attribute__((ext_vector_type(8))) short s16x8;

#define MFMA16(a,b,c) __builtin_amdgcn_mfma_f32_16x16x32_bf16((a),(b),(c),0,0,0)

#define Bc 16
#define Cc 256
#define Nc 4096
#define HDc 32
#define SCALE_F 0.17677669529663688f

__device__ __forceinline__ uint16_t f2bf(float x){
  uint32_t u = __float_as_uint(x);
  return (uint16_t)((u + 0x7fffu + ((u >> 16) & 1u)) >> 16);
}
__device__ __forceinline__ float bf2f(uint16_t b){
  return __uint_as_float(((uint32_t)b) << 16);
}

// ---------------- K0: split weights into bf16 hi/lo ----------------
extern "C" __global__ __launch_bounds__(256) void k0_prep(
    const float* __restrict__ qw, const float* __restrict__ kw, const float* __restrict__ vw,
    uint16_t* __restrict__ qwh, uint16_t* __restrict__ qwl,
    uint16_t* __restrict__ kwh, uint16_t* __restrict__ kwl,
    uint16_t* __restrict__ vwb)
{
  int i = blockIdx.x * 256 + threadIdx.x;
  float q = qw[i]; uint16_t qh = f2bf(q);
  qwh[i] = qh; qwl[i] = f2bf(q - bf2f(qh));
  float k = kw[i]; uint16_t kh = f2bf(k);
  kwh[i] = kh; kwl[i] = f2bf(k - bf2f(kh));
  vwb[i] = f2bf(vw[i]);
}

// ---------------- K1: fused Q,K,V GEMM + spike + BN partials ----------------
// grid (64 n-tiles, 16 batches), 256 threads (4 waves). Wave w owns rows w*64..w*64+63.
// x tile staged transposed in LDS as bf16 hi/lo: [n 0..63][c 0..255], pad XP=264.
extern "C" __global__ __launch_bounds__(256, 2) void k1_qkv(
    const float* __restrict__ x,
    const uint16_t* __restrict__ qwh, const uint16_t* __restrict__ qwl,
    const uint16_t* __restrict__ kwh, const uint16_t* __restrict__ kwl,
    const uint16_t* __restrict__ vwb,
    const float* __restrict__ qvth, const float* __restrict__ kvth,
    uint16_t* __restrict__ qs, uint16_t* __restrict__ ks,
    uint16_t* __restrict__ v0t,
    float* __restrict__ psum, float* __restrict__ psq)
{
  const int XP = 264;
  __shared__ __align__(16) uint16_t xhi[64 * 264];
  __shared__ __align__(16) uint16_t xlo[64 * 264];
  __shared__ float vthq_s[256];
  __shared__ float vthk_s[256];

  const int tid  = threadIdx.x;
  const int lane = tid & 63, wid = tid >> 6;
  const int l15  = lane & 15, lg = lane >> 4;
  const int nb = blockIdx.x, b = blockIdx.y;
  const int nbase = nb * 64;

  vthq_s[tid] = qvth[tid];
  vthk_s[tid] = kvth[tid];

  // ---- stage x tile: transpose + f32 -> bf16 hi/lo ----
  for (int kst = 0; kst < 2; ++kst){
    #pragma unroll
    for (int ni = 0; ni < 4; ++ni){
      const int n  = ni * 16 + l15;
      const int c0 = wid * 64 + kst * 32 + lg * 8;
      const float* xp = x + ((size_t)b * Cc + c0) * Nc + nbase + n;
      s16x8 vh, vl;
      #pragma unroll
      for (int j = 0; j < 8; ++j){
        float v = xp[(size_t)j * Nc];
        uint16_t h = f2bf(v);
        vh[j] = (short)h;
        vl[j] = (short)f2bf(v - bf2f(h));
      }
      const int a = n * XP + c0;
      *(s16x8*)&xhi[a] = vh;
      *(s16x8*)&xlo[a] = vl;
    }
  }
  __syncthreads();

  const int wrow = wid * 64;
  const f32x4 fz = {0.f, 0.f, 0.f, 0.f};

  // ---- Q,K phase: 3-pass bf16x2 (hi*hi + hi*lo + lo*hi) ----
  f32x4 accq[4][4], acck[4][4];
  #pragma unroll
  for (int mi = 0; mi < 4; ++mi)
    #pragma unroll
    for (int ni = 0; ni < 4; ++ni){ accq[mi][ni] = fz; acck[mi][ni] = fz; }

  for (int kc = 0; kc < 256; kc += 32){
    s16x8 bh[4], bl[4];
    #pragma unroll
    for (int ni = 0; ni < 4; ++ni){
      const int a = (ni * 16 + l15) * XP + kc + lg * 8;
      bh[ni] = *(const s16x8*)&xhi[a];
      bl[ni] = *(const s16x8*)&xlo[a];
    }
    #pragma unroll
    for (int mi = 0; mi < 4; ++mi){
      const int wa = (wrow + mi * 16 + l15) * Cc + kc + lg * 8;
      s16x8 aqh = *(const s16x8*)&qwh[wa];
      s16x8 aql = *(const s16x8*)&qwl[wa];
      s16x8 akh = *(const s16x8*)&kwh[wa];
      s16x8 akl = *(const s16x8*)&kwl[wa];
      #pragma unroll
      for (int ni = 0; ni < 4; ++ni){
        accq[mi][ni] = MFMA16(aqh, bh[ni], accq[mi][ni]);
        accq[mi][ni] = MFMA16(aqh, bl[ni], accq[mi][ni]);
        accq[mi][ni] = MFMA16(aql, bh[ni], accq[mi][ni]);
        acck[mi][ni] = MFMA16(akh, bh[ni], acck[mi][ni]);
        acck[mi][ni] = MFMA16(akh, bl[ni], acck[mi][ni]);
        acck[mi][ni] = MFMA16(akl, bh[ni], acck[mi][ni]);
      }
    }
  }

  // ---- spike epilogue: ternary -> bf16 (+-1/0 exact) ----
  #pragma unroll
  for (int mi = 0; mi < 4; ++mi){
    #pragma unroll
    for (int r = 0; r < 4; ++r){
      const int o = wrow + mi * 16 + lg * 4 + r;
      const float vq = vthq_s[o], vk = vthk_s[o];
      uint16_t* qp = qs + ((size_t)b * Cc + o) * Nc + nbase;
      uint16_t* kp = ks + ((size_t)b * Cc + o) * Nc + nbase;
      #pragma unroll
      for (int ni = 0; ni < 4; ++ni){
        const float aq = accq[mi][ni][r];
        const float ak = acck[mi][ni][r];
        float sq = (aq >= vq ? 1.f : 0.f) - (aq <= -vq ? 1.f : 0.f);
        float sk = (ak >= vk ? 1.f : 0.f) - (ak <= -vk ? 1.f : 0.f);
        qp[ni * 16 + l15] = f2bf(sq);
        kp[ni * 16 + l15] = f2bf(sk);
      }
    }
  }

  // ---- V phase: single-pass bf16 ----
  f32x4 accv[4][4];
  #pragma unroll
  for (int mi = 0; mi < 4; ++mi)
    #pragma unroll
    for (int ni = 0; ni < 4; ++ni) accv[mi][ni] = fz;

  for (int kc = 0; kc < 256; kc += 32){
    s16x8 bh[4];
    #pragma unroll
    for (int ni = 0; ni < 4; ++ni)
      bh[ni] = *(const s16x8*)&xhi[(ni * 16 + l15) * XP + kc + lg * 8];
    #pragma unroll
    for (int mi = 0; mi < 4; ++mi){
      s16x8 av = *(const s16x8*)&vwb[(wrow + mi * 16 + l15) * Cc + kc + lg * 8];
      #pragma unroll
      for (int ni = 0; ni < 4; ++ni)
        accv[mi][ni] = MFMA16(av, bh[ni], accv[mi][ni]);
    }
  }

  // ---- BN partial sums (per-channel sum / sumsq over this tile's 64 cols) ----
  const int bid = b * 64 + nb;
  #pragma unroll
  for (int mi = 0; mi < 4; ++mi){
    #pragma unroll
    for (int r = 0; r < 4; ++r){
      float s1 = 0.f, s2 = 0.f;
      #pragma unroll
      for (int ni = 0; ni < 4; ++ni){
        const float v = accv[mi][ni][r];
        s1 += v; s2 += v * v;
      }
      #pragma unroll
      for (int mk = 1; mk < 16; mk <<= 1){
        s1 += __shfl_xor(s1, mk);
        s2 += __shfl_xor(s2, mk);
      }
      if (l15 == 0){
        const int o = wrow + mi * 16 + lg * 4 + r;
        psum[(size_t)bid * Cc + o] = s1;
        psq [(size_t)bid * Cc + o] = s2;
      }
    }
  }

  // ---- transpose accv via LDS scratch (aliases xhi) -> v0t[b][n][c] bf16 ----
  float* scr = (float*)xhi + wid * (64 * 20);   // per-wave [64 n][20 pad]
  for (int mi = 0; mi < 4; ++mi){
    __syncthreads();
    #pragma unroll
    for (int ni = 0; ni < 4; ++ni)
      *(f32x4*)&scr[(ni * 16 + l15) * 20 + lg * 4] = accv[mi][ni];
    __syncthreads();
    const float* sp = scr + lane * 20;
    s16x8 o0, o1;
    #pragma unroll
    for (int j = 0; j < 8; ++j){
      o0[j] = (short)f2bf(sp[j]);
      o1[j] = (short)f2bf(sp[8 + j]);
    }
    uint16_t* dst = v0t + ((size_t)b * Nc + nbase + lane) * Cc + wrow + mi * 16;
    *(s16x8*)dst = o0;
    *(s16x8*)(dst + 8) = o1;
  }
}

// ---------------- K2: finalize BN -> scale/shift ----------------
extern "C" __global__ __launch_bounds__(256) void k2_stats(
    const float* __restrict__ psum, const float* __restrict__ psq,
    const float* __restrict__ gamma, const float* __restrict__ beta,
    float* __restrict__ sc, float* __restrict__ sh)
{
  const int c = threadIdx.x;
  float s1 = 0.f, s2 = 0.f;
  for (int i = 0; i < 1024; ++i){
    s1 += psum[i * 256 + c];
    s2 += psq [i * 256 + c];
  }
  const float inv = 1.f / 65536.f;
  const float mean = s1 * inv;
  const float var  = s2 * inv - mean * mean;
  const float s = gamma[c] * rsqrtf(var + 1e-5f);
  sc[c] = s;
  sh[c] = beta[c] - mean * s;
}

// ---------------- K3: QK^T (exact) + softmax + fold into M, bias ----------------
// grid (8 heads, 16 batches), 512 threads (8 waves). Wave w: 512 n's of the K-contraction,
// then rows w*32..w*32+31 of M.
extern "C" __global__ __launch_bounds__(512, 2) void k3_attn(
    const uint16_t* __restrict__ qs, const uint16_t* __restrict__ ks,
    const float* __restrict__ pw, const float* __restrict__ sc, const float* __restrict__ sh,
    float* __restrict__ Mp, float* __restrict__ bias)
{
  __shared__ float Spart[8][32 * 33];
  __shared__ float Sf[32 * 33];
  __shared__ __align__(16) uint16_t attn_t[32 * 40];  // [e][d] bf16

  const int h = blockIdx.x, b = blockIdx.y;
  const int tid = threadIdx.x;
  const int lane = tid & 63, w = tid >> 6;
  const int l15 = lane & 15, lg = lane >> 4;

  const f32x4 fz = {0.f, 0.f, 0.f, 0.f};
  f32x4 acc[2][2] = {{fz, fz}, {fz, fz}};
  const uint16_t* qb = qs + ((size_t)b * Cc + h * HDc) * Nc;
  const uint16_t* kb = ks + ((size_t)b * Cc + h * HDc) * Nc;
  const int n0base = w * 512;
  for (int n0 = n0base; n0 < n0base + 512; n0 += 32){
    const int off = n0 + lg * 8;
    s16x8 a0 = *(const s16x8*)&qb[(l15) * Nc + off];
    s16x8 a1 = *(const s16x8*)&qb[(16 + l15) * Nc + off];
    s16x8 b0 = *(const s16x8*)&kb[(l15) * Nc + off];
    s16x8 b1 = *(const s16x8*)&kb[(16 + l15) * Nc + off];
    acc[0][0] = MFMA16(a0, b0, acc[0][0]);
    acc[0][1] = MFMA16(a0, b1, acc[0][1]);
    acc[1][0] = MFMA16(a1, b0, acc[1][0]);
    acc[1][1] = MFMA16(a1, b1, acc[1][1]);
  }
  #pragma unroll
  for (int di = 0; di < 2; ++di)
    #pragma unroll
    for (int ei = 0; ei < 2; ++ei)
      #pragma unroll
      for (int r = 0; r < 4; ++r)
        Spart[w][(di * 16 + lg * 4 + r) * 33 + ei * 16 + l15] = acc[di][ei][r];
  __syncthreads();

  for (int e = tid; e < 1024; e += 512){
    const int row = e >> 5, col = e & 31;
    float s = 0.f;
    #pragma unroll
    for (int ww = 0; ww < 8; ++ww) s += Spart[ww][row * 33 + col];
    Sf[row * 33 + col] = s * SCALE_F;
  }
  __syncthreads();

  if (tid < 32){
    const int d = tid;
    float mx = -1e30f;
    #pragma unroll
    for (int e = 0; e < 32; ++e) mx = fmaxf(mx, Sf[d * 33 + e]);
    float p[32]; float sum = 0.f;
    #pragma unroll
    for (int e = 0; e < 32; ++e){ p[e] = expf(Sf[d * 33 + e] - mx); sum += p[e]; }
    const float inv = 1.f / sum;
    #pragma unroll
    for (int e = 0; e < 32; ++e) attn_t[e * 40 + d] = f2bf(p[e] * inv);
  }
  __syncthreads();

  // M_h[o,e] = sum_d pw[o, h*32+d] * attn[d,e]   (one MFMA K-step, K=32)
  s16x8 bfr[2];
  #pragma unroll
  for (int ei = 0; ei < 2; ++ei)
    bfr[ei] = *(const s16x8*)&attn_t[(ei * 16 + l15) * 40 + lg * 8];

  f32x4 m[2][2] = {{fz, fz}, {fz, fz}};
  #pragma unroll
  for (int mi = 0; mi < 2; ++mi){
    const float* ap = pw + ((size_t)(w * 32 + mi * 16 + l15)) * Cc + h * HDc + lg * 8;
    f32x4 a0 = *(const f32x4*)ap;
    f32x4 a1 = *(const f32x4*)(ap + 4);
    s16x8 af;
    #pragma unroll
    for (int j = 0; j < 4; ++j){ af[j] = (short)f2bf(a0[j]); af[4 + j] = (short)f2bf(a1[j]); }
    #pragma unroll
    for (int ei = 0; ei < 2; ++ei)
      m[mi][ei] = MFMA16(af, bfr[ei], m[mi][ei]);
  }

  const float sc0 = sc[h * HDc + l15],      sc1 = sc[h * HDc + 16 + l15];
  const float sh0 = sh[h * HDc + l15],      sh1 = sh[h * HDc + 16 + l15];
  #pragma unroll
  for (int mi = 0; mi < 2; ++mi){
    #pragma unroll
    for (int r = 0; r < 4; ++r){
      const int o = w * 32 + mi * 16 + lg * 4 + r;
      float* mp = Mp + ((size_t)b * Cc + o) * Cc + h * HDc;
      const float m0 = m[mi][0][r], m1 = m[mi][1][r];
      mp[l15]      = m0 * sc0;
      mp[16 + l15] = m1 * sc1;
      float bb = m0 * sh0 + m1 * sh1;
      #pragma unroll
      for (int mk = 1; mk < 16; mk <<= 1) bb += __shfl_xor(bb, mk);
      if (l15 == 0) atomicAdd(&bias[b * Cc + o], bb);
    }
  }
}

// ---------------- K4: out = M_b @ v0t + bias + x ----------------
extern "C" __global__ __launch_bounds__(256, 2) void k4_proj(
    const float* __restrict__ Mp, const uint16_t* __restrict__ v0t,
    const float* __restrict__ bias, const float* __restrict__ x,
    float* __restrict__ out)
{
  const int tid = threadIdx.x;
  const int lane = tid & 63, wid = tid >> 6;
  const int l15 = lane & 15, lg = lane >> 4;
  const int nb = blockIdx.x, b = blockIdx.y;
  const int nbase = nb * 64, wrow = wid * 64;

  const f32x4 fz = {0.f, 0.f, 0.f, 0.f};
  f32x4 acc[4][4];
  #pragma unroll
  for (int mi = 0; mi < 4; ++mi)
    #pragma unroll
    for (int ni = 0; ni < 4; ++ni) acc[mi][ni] = fz;

  for (int kc = 0; kc < 256; kc += 32){
    s16x8 bf[4];
    #pragma unroll
    for (int ni = 0; ni < 4; ++ni)
      bf[ni] = *(const s16x8*)&v0t[((size_t)b * Nc + nbase + ni * 16 + l15) * Cc + kc + lg * 8];
    #pragma unroll
    for (int mi = 0; mi < 4; ++mi){
      const float* ap = Mp + ((size_t)b * Cc + wrow + mi * 16 + l15) * Cc + kc + lg * 8;
      f32x4 a0 = *(const f32x4*)ap;
      f32x4 a1 = *(const f32x4*)(ap + 4);
      s16x8 af;
      #pragma unroll
      for (int j = 0; j < 4; ++j){ af[j] = (short)f2bf(a0[j]); af[4 + j] = (short)f2bf(a1[j]); }
      #pragma unroll
      for (int ni = 0; ni < 4; ++ni)
        acc[mi][ni] = MFMA16(af, bf[ni], acc[mi][ni]);
    }
  }

  #pragma unroll
  for (int mi = 0; mi < 4; ++mi){
    #pragma unroll
    for (int r = 0; r < 4; ++r){
      const int o = wrow + mi * 16 + lg * 4 + r;
      const float bb = bias[b * Cc + o];
      const size_t base = ((size_t)b * Cc + o) * Nc + nbase;
      #pragma unroll
      for (int ni = 0; ni < 4; ++ni){
        const size_t aidx = base + ni * 16 + l15;
        out[aidx] = acc[mi][ni][r] + bb + x[aidx];
      }
    }
  }
}

// ---------------- launch ----------------
extern "C" void kernel_launch(void* const* d_in, const int* in_sizes, int n_in,
                              void* d_out, int out_size, void* d_ws, size_t ws_size,
                              hipStream_t stream)
{
  (void)in_sizes; (void)n_in; (void)out_size; (void)ws_size;
  const float* x      = (const float*)d_in[0];
  const float* q_w    = (const float*)d_in[1];
  const float* k_w    = (const float*)d_in[2];
  const float* v_w    = (const float*)d_in[3];
  const float* proj_w = (const float*)d_in[4];
  const float* gamma  = (const float*)d_in[5];
  const float* beta   = (const float*)d_in[6];
  const float* q_vth  = (const float*)d_in[7];
  const float* k_vth  = (const float*)d_in[8];
  float* out = (float*)d_out;

  char* ws = (char*)d_ws;
  uint16_t* qwh = (uint16_t*)(ws + 0);
  uint16_t* qwl = (uint16_t*)(ws + 131072);
  uint16_t* kwh = (uint16_t*)(ws + 262144);
  uint16_t* kwl = (uint16_t*)(ws + 393216);
  uint16_t* vwb = (uint16_t*)(ws + 524288);
  uint16_t* v0t = (uint16_t*)(ws + 655360);           // 32 MiB
  float* psum   = (float*)(ws + 34209792);            // 1 MiB
  float* psq    = (float*)(ws + 35258368);            // 1 MiB
  float* sc     = (float*)(ws + 36306944);
  float* sh     = (float*)(ws + 36307968);
  float* Mp     = (float*)(ws + 36308992);            // 4 MiB
  float* bias   = (float*)(ws + 40503296);            // 16 KiB

  // qs/ks live in d_out (64 MiB) as scratch; K4 overwrites d_out last.
  uint16_t* qs = (uint16_t*)d_out;
  uint16_t* ks = (uint16_t*)((char*)d_out + 33554432);

  hipMemsetAsync(bias, 0, 16 * 256 * sizeof(float), stream);

  k0_prep<<<256, 256, 0, stream>>>(q_w, k_w, v_w, qwh, qwl, kwh, kwl, vwb);
  k1_qkv<<<dim3(64, 16), 256, 0, stream>>>(x, qwh, qwl, kwh, kwl, vwb,
                                           q_vth, k_vth, qs, ks, v0t, psum, psq);
  k2_stats<<<1, 256, 0, stream>>>(psum, psq, gamma, beta, sc, sh);
  k3_attn<<<dim3(8, 16), 512, 0, stream>>>(qs, ks, proj_w, sc, sh, Mp, bias);
  k4_proj<<<dim3(64, 16), 256, 0, stream>>>(Mp, v0t, bias, x, out);
}